// Round 5
// baseline (1437.001 us; speedup 1.0000x reference)
//
#include <hip/hip_runtime.h>

#define NN 650
#define NE 100000

typedef short bf16x8_t __attribute__((ext_vector_type(8)));
typedef short s16x4_t __attribute__((ext_vector_type(4)));
typedef float f32x4_t __attribute__((ext_vector_type(4)));

__device__ __forceinline__ unsigned short f2bf(float f) {
  union { float f; unsigned u; } x; x.f = f;
  unsigned r = x.u + 0x7fffu + ((x.u >> 16) & 1u);
  return (unsigned short)(r >> 16);
}
__device__ __forceinline__ float bf2f(unsigned short u) {
  union { unsigned u; float f; } x; x.u = ((unsigned)u) << 16; return x.f;
}

typedef const __attribute__((address_space(1))) unsigned int* gptr_t;
typedef __attribute__((address_space(3))) unsigned int* lptr_t;
__device__ __forceinline__ void gl_lds16(const unsigned short* g, unsigned short* l) {
  __builtin_amdgcn_global_load_lds((gptr_t)g, (lptr_t)l, 16, 0, 0);
}

// ---------------- adjacency build ----------------
__global__ void k_scatter(const int* __restrict__ src, const int* __restrict__ dst,
                          float* __restrict__ C, float* __restrict__ deg) {
  int e = blockIdx.x * 256 + threadIdx.x;
  if (e < NE) {
    int s = src[e], d = dst[e];
    atomicAdd(&C[d * NN + s], 1.0f);
    atomicAdd(&deg[d], 1.0f);
  }
}

// Cn[i][j] = C[i][j]/max(deg[i],1); 768 rows x 672 cols, zero-padded, bf16
__global__ void k_adj_norm(const float* __restrict__ C, const float* __restrict__ deg,
                           unsigned short* __restrict__ Cn) {
  int idx = blockIdx.x * 256 + threadIdx.x;
  if (idx >= 768 * 672) return;
  int i = idx / 672, j = idx - i * 672;
  float v = (i < NN && j < NN) ? C[i * NN + j] / fmaxf(deg[i], 1.0f) : 0.0f;
  Cn[idx] = f2bf(v);
}

// ---------------- fused f32->bf16 converts (12 jobs, 1 launch) ----------------
#define MAXJ 12
struct CvtDesc { const float* src; unsigned short* dst; int Mvalid, Kin, ldi, off, ldo, nElem, nblk; };
struct CvtPack { CvtDesc d[MAXJ]; };
__global__ void k_cvt_all(CvtPack P) {
  int b = blockIdx.x;
  int j = 0;
  while (b >= P.d[j].nblk) { b -= P.d[j].nblk; ++j; }
  const CvtDesc D = P.d[j];
  int idx = b * 256 + threadIdx.x;
  if (idx >= D.nElem) return;
  int r = idx / D.ldo, c = idx - r * D.ldo;
  D.dst[idx] = (r < D.Mvalid && c < D.Kin) ? f2bf(D.src[(size_t)r * D.ldi + D.off + c]) : (unsigned short)0;
}

// ---------------- LDS-tiled transpose: out[c][r] = in[r][c] ----------------
__global__ void k_ttr(const unsigned short* __restrict__ in, unsigned short* __restrict__ out,
                      int ldi, int ldo) {
  __shared__ unsigned short tile[64][65];
  const int c0 = blockIdx.x * 64, r0 = blockIdx.y * 64;
  const int t = threadIdx.x;
  const int rl = t >> 4, cl = (t & 15) * 4;
#pragma unroll
  for (int rr = 0; rr < 4; ++rr) {
    s16x4_t v = *(const s16x4_t*)(in + (size_t)(r0 + rl + rr * 16) * ldi + c0 + cl);
#pragma unroll
    for (int j = 0; j < 4; ++j) tile[rl + rr * 16][cl + j] = (unsigned short)v[j];
  }
  __syncthreads();
  if (r0 + cl < ldo) {
#pragma unroll
    for (int cc = 0; cc < 4; ++cc) {
      int crow = rl + cc * 16;
      unsigned short o[4] = { tile[cl + 0][crow], tile[cl + 1][crow],
                              tile[cl + 2][crow], tile[cl + 3][crow] };
      *(s16x4_t*)(out + (size_t)(c0 + crow) * ldo + r0 + cl) = *(s16x4_t*)o;
    }
  }
}

// ---- P chunk: P[local][k] = relu(Pa[(r0+local)/400][k] + Po[(r0+local)%400][k]) ----
__global__ void k_pgen(const float* __restrict__ Pa, const float* __restrict__ Po,
                       unsigned short* __restrict__ P, int r0, int rows) {
  int g = blockIdx.x * 256 + threadIdx.x;        // group of 8 elements
  if (g >= rows * 152) return;
  int lp = g / 152, k = (g - lp * 152) * 8;
  int p = r0 + lp;
  unsigned short t8[8];
  if (p < 100000) {
    int a = p / 400, o = p - a * 400;
    const float* pa = Pa + (size_t)a * 1216 + k;
    const float* po = Po + (size_t)o * 1216 + k;
    float4 x1 = *(const float4*)(pa);
    float4 x2 = *(const float4*)(pa + 4);
    float4 y1 = *(const float4*)(po);
    float4 y2 = *(const float4*)(po + 4);
    t8[0] = f2bf(fmaxf(x1.x + y1.x, 0.f)); t8[1] = f2bf(fmaxf(x1.y + y1.y, 0.f));
    t8[2] = f2bf(fmaxf(x1.z + y1.z, 0.f)); t8[3] = f2bf(fmaxf(x1.w + y1.w, 0.f));
    t8[4] = f2bf(fmaxf(x2.x + y2.x, 0.f)); t8[5] = f2bf(fmaxf(x2.y + y2.y, 0.f));
    t8[6] = f2bf(fmaxf(x2.z + y2.z, 0.f)); t8[7] = f2bf(fmaxf(x2.w + y2.w, 0.f));
  } else {
#pragma unroll
    for (int j = 0; j < 8; ++j) t8[j] = 0;
  }
  *(bf16x8_t*)(P + (size_t)lp * 1216 + k) = *(bf16x8_t*)t8;
}

// ---- finalize LN stats: S -> mean, SS -> rsqrt(var+eps) ----
__global__ void k_stats_fin(float* __restrict__ S, float* __restrict__ SS) {
  int i = blockIdx.x * 256 + threadIdx.x;
  if (i >= 100096) return;
  float s = S[i], ss = SS[i];
  float m = s * (1.0f / 800.0f);
  float var = ss * (1.0f / 800.0f) - m * m;
  S[i] = m;
  SS[i] = rsqrtf(fmaxf(var, 0.f) + 1e-5f);
}

// ---- iG = bf16(i * gp); c1 = sum(i*gp); c2 = sum(i*bpn). 256 rows, 128 thr/row ----
__global__ void k_prep_i(const unsigned short* __restrict__ iB,
                         const float* __restrict__ gp, const float* __restrict__ bpn,
                         unsigned short* __restrict__ iG,
                         float* __restrict__ c1, float* __restrict__ c2) {
  const int row = blockIdx.x, t = threadIdx.x;   // 128 threads
  float s1 = 0.f, s2 = 0.f;
  if (t < 100) {
    bf16x8_t v = *(const bf16x8_t*)(iB + (size_t)row * 800 + t * 8);
    unsigned short o[8];
#pragma unroll
    for (int j = 0; j < 8; ++j) {
      float f = bf2f((unsigned short)v[j]);
      float g = gp[t * 8 + j];
      s1 += f * g; s2 += f * bpn[t * 8 + j];
      o[j] = f2bf(f * g);
    }
    *(bf16x8_t*)(iG + (size_t)row * 800 + t * 8) = *(bf16x8_t*)o;
  }
#pragma unroll
  for (int off = 32; off > 0; off >>= 1) { s1 += __shfl_down(s1, off); s2 += __shfl_down(s2, off); }
  __shared__ float sh[4];
  int w = t >> 6, lane = t & 63;
  if (lane == 0) { sh[w] = s1; sh[2 + w] = s2; }
  __syncthreads();
  if (t == 0) { c1[row] = sh[0] + sh[1]; c2[row] = sh[2] + sh[3]; }
}

// ---------------- m97-style MFMA GEMM, paired-tile double-buffer ----------------
// Per barrier window (one __syncthreads per TWO BK=32 tiles):
//   __syncthreads()  [drains previous pair's staging; WAR-safe point]
//   -> issue staging of tiles p+2,p+3 into the other buffer set
//   -> compute tile p, then tile p+1.
// Staging in-flight time ~= 2 tiles of compute; barrier-drain count halved.
// Only compiler-known sync (__syncthreads = vmcnt(0)+lgkmcnt(0)+s_barrier):
// deterministic by construction. LDS = 64 KB (2 sets x 2 tiles x A,B).
// swz=1: bijective XCD swizzle (x-fastest siblings share one XCD's L2).
// QST=1: fused per-row sum/sumsq epilogue (LN stats) via shfl_xor + atomicAdd.
#define BK 32
template<int OUT_BF, int RELU, int LNF, int QST>
__launch_bounds__(256)
__global__ void k_gemm128(const unsigned short* __restrict__ A,
                          const unsigned short* __restrict__ B,
                          const float* __restrict__ bias,
                          const float* __restrict__ addb,
                          void* __restrict__ Cout,
                          int K, int ldc,
                          int Mvalid, int Nvalid, int Nstore, int swap, int swz,
                          const float* __restrict__ lnm, const float* __restrict__ lninv,
                          const float* __restrict__ lnc1, const float* __restrict__ lnc2,
                          float* __restrict__ sumP, float* __restrict__ ssP) {
  __shared__ unsigned short As[2][2][128 * BK];
  __shared__ unsigned short Bs[2][2][128 * BK];
  const int tid = threadIdx.x;
  const int w = tid >> 6, lane = tid & 63;
  int bx = blockIdx.x, by = blockIdx.y;
  if (swz) {
    int T = gridDim.x * gridDim.y;
    int flat = blockIdx.x + gridDim.x * blockIdx.y;
    int xcd = flat & 7, s = flat >> 3;
    int qq = T >> 3, rr = T & 7;
    int slot = (xcd < rr ? xcd * (qq + 1) : rr * (qq + 1) + (xcd - rr) * qq) + s;
    bx = slot % gridDim.x; by = slot / gridDim.x;
  }
  const int bm = swap ? by : bx;
  const int bn = swap ? bx : by;
  const int m0 = bm * 128, n0 = bn * 128;
  const int wm = w & 1, wn = w >> 1;
  const int lr = lane & 15, q = lane >> 4;

  const int srow = w * 32 + (lane >> 2);
  const int scol = (lane & 3) * 8;
  const unsigned short* Abase = A + (size_t)(m0 + srow) * K + scol;
  const unsigned short* Bbase = B + (size_t)(n0 + srow) * K + scol;
  const int so0 = (w * 32) * BK;
  const int so1 = (w * 32 + 16) * BK;

  f32x4_t acc[4][4];
#pragma unroll
  for (int r = 0; r < 4; ++r)
#pragma unroll
    for (int t = 0; t < 4; ++t) { f32x4_t z = {0.f, 0.f, 0.f, 0.f}; acc[r][t] = z; }

  const int nt = K / BK;   // all call sites have K >= 512 -> nt >= 16

  // stage tile kt into buffer (set, slot)
  auto stage = [&](int kt, int set, int slot) {
    const unsigned short* ag = Abase + kt * BK;
    const unsigned short* bg = Bbase + kt * BK;
    unsigned short* da = &As[set][slot][0];
    unsigned short* db = &Bs[set][slot][0];
    gl_lds16(ag, da + so0); gl_lds16(ag + 16 * (size_t)K, da + so1);
    gl_lds16(bg, db + so0); gl_lds16(bg + 16 * (size_t)K, db + so1);
  };
  // compute one tile from buffer (set, slot)
  auto compute = [&](int set, int slot) {
    bf16x8_t af[4], bfv[4];
#pragma unroll
    for (int r = 0; r < 4; ++r)
      af[r] = *(const bf16x8_t*)(&As[set][slot][(wm * 64 + r * 16 + lr) * BK + q * 8]);
#pragma unroll
    for (int tt = 0; tt < 4; ++tt)
      bfv[tt] = *(const bf16x8_t*)(&Bs[set][slot][(wn * 64 + tt * 16 + lr) * BK + q * 8]);
#pragma unroll
    for (int r = 0; r < 4; ++r)
#pragma unroll
      for (int tt = 0; tt < 4; ++tt)
        acc[r][tt] = __builtin_amdgcn_mfma_f32_16x16x32_bf16(af[r], bfv[tt], acc[r][tt], 0, 0, 0);
  };

  // prologue: stage pair 0 (tiles 0,1) into set 0
  stage(0, 0, 0);
  if (1 < nt) stage(1, 0, 1);

  for (int p = 0; p < nt; p += 2) {
    const int st = (p >> 1) & 1;
    __syncthreads();                 // drains pair-p staging; WAR-safe for restage
    const int so_ = st ^ 1;
    if (p + 2 < nt) stage(p + 2, so_, 0);   // lands while we compute this pair
    if (p + 3 < nt) stage(p + 3, so_, 1);
    compute(st, 0);                  // tile p
    if (p + 1 < nt) compute(st, 1);  // tile p+1
  }

  if (QST) {
    // epilogue with fused row-stats (store + per-row sum / sumsq of acc+bias)
#pragma unroll
    for (int r = 0; r < 4; ++r) {
#pragma unroll
      for (int e = 0; e < 4; ++e) {
        const int gm = m0 + wm * 64 + r * 16 + q * 4 + e;
        float s = 0.f, ss = 0.f;
#pragma unroll
        for (int t = 0; t < 4; ++t) {
          const int gn = n0 + wn * 64 + t * 16 + lr;
          float v = 0.f;
          if (gm < Mvalid && gn < Nvalid) v = acc[r][t][e] + bias[gn];
          if (gn < Nstore)
            ((unsigned short*)Cout)[(size_t)gm * ldc + gn] = f2bf(v);
          s += v; ss += v * v;
        }
#pragma unroll
        for (int m = 1; m < 16; m <<= 1) {
          s += __shfl_xor(s, m);
          ss += __shfl_xor(ss, m);
        }
        if (lr == 0 && gm < Mvalid) {
          atomicAdd(&sumP[gm], s);
          atomicAdd(&ssP[gm], ss);
        }
      }
    }
  } else {
#pragma unroll
    for (int r = 0; r < 4; ++r) {
#pragma unroll
      for (int t = 0; t < 4; ++t) {
#pragma unroll
        for (int e = 0; e < 4; ++e) {
          int gm = m0 + wm * 64 + r * 16 + q * 4 + e;
          int gn = n0 + wn * 64 + t * 16 + lr;
          if (gn < Nstore) {
            float v = 0.f;
            if (gm < Mvalid && gn < Nvalid) {
              v = acc[r][t][e];
              if (LNF) {
                v = lninv[gn] * (v - lnm[gn] * lnc1[gm]) + lnc2[gm];
              } else {
                if (bias) v += bias[gn];
                if (addb) v += addb[(size_t)gm * ldc + gn];
                if (RELU) v = fmaxf(v, 0.f);
              }
            }
            if (OUT_BF) ((unsigned short*)Cout)[(size_t)gm * ldc + gn] = f2bf(v);
            else        ((float*)Cout)[(size_t)gm * ldc + gn] = v;
          }
        }
      }
    }
  }
}

// ---------------- LayerNorm over D=800 (f32 in, bf16 out) — image branch only ----------------
__global__ void k_ln_img(const float* __restrict__ in, unsigned short* __restrict__ out,
                         const float* __restrict__ g, const float* __restrict__ b) {
  const int row = blockIdx.x, t = threadIdx.x;
  float v[4]; float s = 0.f, ss = 0.f; int j = 0;
  for (int idx = t; idx < 800; idx += 256, ++j) {
    float x = in[(size_t)row * 800 + idx];
    v[j] = x; s += x; ss += x * x;
  }
#pragma unroll
  for (int off = 32; off > 0; off >>= 1) {
    s += __shfl_down(s, off);
    ss += __shfl_down(ss, off);
  }
  __shared__ float sh[8];
  int wave = t >> 6, lane = t & 63;
  if (lane == 0) { sh[wave] = s; sh[4 + wave] = ss; }
  __syncthreads();
  if (t == 0) {
    float S = sh[0] + sh[1] + sh[2] + sh[3];
    float SS = sh[4] + sh[5] + sh[6] + sh[7];
    float m = S * (1.0f / 800.0f);
    float var = SS * (1.0f / 800.0f) - m * m;
    sh[0] = m; sh[1] = rsqrtf(fmaxf(var, 0.f) + 1e-5f);
  }
  __syncthreads();
  float m = sh[0], inv = sh[1];
  j = 0;
  for (int idx = t; idx < 800; idx += 256, ++j) {
    float y = (v[j] - m) * inv * g[idx] + b[idx];
    out[(size_t)row * 800 + idx] = f2bf(y);
  }
}

// ---------------- host ----------------
extern "C" void kernel_launch(void* const* d_in, const int* in_sizes, int n_in,
                              void* d_out, int out_size, void* d_ws, size_t ws_size,
                              hipStream_t stream) {
  (void)in_sizes; (void)n_in; (void)out_size; (void)ws_size;
  const float* img  = (const float*)d_in[0];
  const float* nodes= (const float*)d_in[1];
  const int* esrc   = (const int*)d_in[2];
  const int* edst   = (const int*)d_in[3];
  const float* W1l  = (const float*)d_in[4];
  const float* b1   = (const float*)d_in[5];
  const float* W1r  = (const float*)d_in[6];
  const float* W2l  = (const float*)d_in[7];
  const float* b2   = (const float*)d_in[8];
  const float* W2r  = (const float*)d_in[9];
  const float* Wp1  = (const float*)d_in[10];
  const float* bp1  = (const float*)d_in[11];
  const float* Wp2  = (const float*)d_in[12];
  const float* bp2  = (const float*)d_in[13];
  const float* gp   = (const float*)d_in[14];
  const float* bpn  = (const float*)d_in[15];
  const float* Wi1  = (const float*)d_in[16];
  const float* bi1  = (const float*)d_in[17];
  const float* Wi2  = (const float*)d_in[18];
  const float* bi2  = (const float*)d_in[19];
  const float* Wi3  = (const float*)d_in[20];
  const float* bi3  = (const float*)d_in[21];
  const float* gi   = (const float*)d_in[22];
  const float* binp = (const float*)d_in[23];

  char* wsp = (char*)d_ws;
  auto alloc = [&](size_t bytes) -> void* {
    void* p = (void*)wsp; wsp += (bytes + 255) & ~(size_t)255; return p;
  };
  // persistent (live across the pair stage)
  unsigned short* onB    = (unsigned short*)alloc((size_t)768 * 512 * 2);
  unsigned short* Wp1LB  = (unsigned short*)alloc((size_t)1280 * 512 * 2);
  unsigned short* Wp1RB  = (unsigned short*)alloc((size_t)1280 * 512 * 2);
  unsigned short* Wp2B   = (unsigned short*)alloc((size_t)896 * 1216 * 2);
  float* PaB             = (float*)alloc((size_t)256 * 1216 * 4);
  float* PoB             = (float*)alloc((size_t)512 * 1216 * 4);
  unsigned short* imgB   = (unsigned short*)alloc((size_t)256 * 2048 * 2);
  unsigned short* Wi1B   = (unsigned short*)alloc((size_t)768 * 2048 * 2);
  unsigned short* Wi2B   = (unsigned short*)alloc((size_t)1024 * 768 * 2);
  unsigned short* Wi3B   = (unsigned short*)alloc((size_t)896 * 1024 * 2);
  unsigned short* i1B    = (unsigned short*)alloc((size_t)256 * 768 * 2);
  unsigned short* i2B    = (unsigned short*)alloc((size_t)256 * 1024 * 2);
  float* i3F             = (float*)alloc((size_t)256 * 800 * 4);
  unsigned short* iB     = (unsigned short*)alloc((size_t)256 * 800 * 2);
  unsigned short* iG     = (unsigned short*)alloc((size_t)256 * 800 * 2);
  float* c1B             = (float*)alloc(256 * 4);
  float* c2B             = (float*)alloc(256 * 4);
  float* mArr            = (float*)alloc((size_t)100096 * 4);
  float* ivArr           = (float*)alloc((size_t)100096 * 4);
  unsigned short* qB     = (unsigned short*)alloc((size_t)100096 * 800 * 2);

  // node-stage scratch overlays the qB region (dead before first qB write)
  char* swp = (char*)qB;
  auto salloc = [&](size_t bytes) -> void* {
    void* p = (void*)swp; swp += (bytes + 255) & ~(size_t)255; return p;
  };
  float* adjC            = (float*)salloc((size_t)NN * NN * 4);
  float* deg             = (float*)salloc(NN * 4);
  unsigned short* Cn     = (unsigned short*)salloc((size_t)768 * 672 * 2);
  unsigned short* nodesB = (unsigned short*)salloc((size_t)768 * 512 * 2);
  unsigned short* nodesT = (unsigned short*)salloc((size_t)512 * 672 * 2);
  unsigned short* agg1   = (unsigned short*)salloc((size_t)768 * 512 * 2);
  float* tmp1            = (float*)salloc((size_t)768 * 4096 * 4);
  unsigned short* hB     = (unsigned short*)salloc((size_t)768 * 4096 * 2);
  unsigned short* hT     = (unsigned short*)salloc((size_t)4096 * 672 * 2);
  unsigned short* agg2   = (unsigned short*)salloc((size_t)768 * 4096 * 2);
  float* tmp2            = (float*)salloc((size_t)768 * 512 * 4);
  unsigned short* W1lB   = (unsigned short*)salloc((size_t)4096 * 512 * 2);
  unsigned short* W1rB   = (unsigned short*)salloc((size_t)4096 * 512 * 2);
  unsigned short* W2lB   = (unsigned short*)salloc((size_t)512 * 4096 * 2);
  unsigned short* W2rB   = (unsigned short*)salloc((size_t)512 * 4096 * 2);

  // P chunk scratch lives in d_out (102.4 MB; scratch-legal until the final GEMM)
  unsigned short* Pch = (unsigned short*)d_out;  // max 262*128 rows * 1216 * 2 = 81.6 MB

  hipMemsetAsync(adjC, 0, (size_t)NN * NN * 4, stream);
  hipMemsetAsync(deg, 0, NN * 4, stream);
  hipMemsetAsync(mArr, 0, (size_t)100096 * 4, stream);   // row-sum accumulators
  hipMemsetAsync(ivArr, 0, (size_t)100096 * 4, stream);  // row-sumsq accumulators

  k_scatter<<<dim3((NE + 255) / 256), 256, 0, stream>>>(esrc, edst, adjC, deg);
  k_adj_norm<<<dim3((768 * 672 + 255) / 256), 256, 0, stream>>>(adjC, deg, Cn);

  // ---- fused converts (one launch) ----
  {
    CvtPack pk; int nj = 0, tot = 0;
    auto addj = [&](const float* s, unsigned short* d, int Mv, int Mp, int Kin, int ldi, int off, int ldo) {
      int ne = Mp * ldo, nb = (ne + 255) / 256;
      pk.d[nj++] = { s, d, Mv, Kin, ldi, off, ldo, ne, nb };
      tot += nb;
    };
    addj(nodes, nodesB, 650, 768, 512, 512, 0, 512);
    addj(W1l, W1lB, 4096, 4096, 512, 512, 0, 512);
    addj(W1r, W1rB, 4096, 4096, 512, 512, 0, 512);
    addj(W2l, W2lB, 512, 512, 4096, 4096, 0, 4096);
    addj(W2r, W2rB, 512, 512, 4096, 4096, 0, 4096);
    addj(Wp1, Wp1LB, 1200, 1280, 512, 1024, 0, 512);
    addj(Wp1, Wp1RB, 1200, 1280, 512, 1024, 512, 512);
    addj(Wp2, Wp2B, 800, 896, 1200, 1200, 0, 1216);
    addj(Wi1, Wi1B, 768, 768, 2048, 2048, 0, 2048);
    addj(Wi2, Wi2B, 1000, 1024, 768, 768, 0, 768);
    addj(Wi3, Wi3B, 800, 896, 1000, 1000, 0, 1024);
    addj(img, imgB, 256, 256, 2048, 2048, 0, 2048);
    k_cvt_all<<<dim3(tot), 256, 0, stream>>>(pk);
  }

  // nodesT[feat][node] from nodesB; out 512 x 672
  k_ttr<<<dim3(512 / 64, (672 + 63) / 64), 256, 0, stream>>>(nodesB, nodesT, 512, 672);

#define NUL nullptr, nullptr, nullptr, nullptr, nullptr, nullptr
  // ---- node stage (scratch region) ----
  k_gemm128<1, 0, 0, 0><<<dim3(6, 4), 256, 0, stream>>>(Cn, nodesT, nullptr, nullptr, agg1, 672, 512, 650, 512, 512, 0, 0, NUL);
  k_gemm128<0, 0, 0, 0><<<dim3(6, 32), 256, 0, stream>>>(agg1, W1lB, b1, nullptr, tmp1, 512, 4096, 650, 4096, 4096, 0, 0, NUL);
  k_gemm128<1, 1, 0, 0><<<dim3(6, 32), 256, 0, stream>>>(nodesB, W1rB, nullptr, tmp1, hB, 512, 4096, 650, 4096, 4096, 0, 0, NUL);
  k_ttr<<<dim3(4096 / 64, (672 + 63) / 64), 256, 0, stream>>>(hB, hT, 4096, 672);
  k_gemm128<1, 0, 0, 0><<<dim3(6, 32), 256, 0, stream>>>(Cn, hT, nullptr, nullptr, agg2, 672, 4096, 650, 4096, 4096, 0, 0, NUL);
  k_gemm128<0, 0, 0, 0><<<dim3(6, 4), 256, 0, stream>>>(agg2, W2lB, b2, nullptr, tmp2, 4096, 512, 650, 512, 512, 0, 0, NUL);
  k_gemm128<1, 0, 0, 0><<<dim3(6, 4), 256, 0, stream>>>(hB, W2rB, nullptr, tmp2, onB, 4096, 512, 650, 512, 512, 0, 0, NUL);
  // Pa = attr @ Wp1L.T + bp1 ; Po = obj @ Wp1R.T (f32, ld 1216, cols 1200..1215 zero)
  k_gemm128<0, 0, 0, 0><<<dim3(2, 10), 256, 0, stream>>>(onB, Wp1LB, bp1, nullptr, PaB, 512, 1216, 250, 1200, 1216, 0, 0, NUL);
  k_gemm128<0, 0, 0, 0><<<dim3(4, 10), 256, 0, stream>>>(onB + 250 * 512, Wp1RB, nullptr, nullptr, PoB, 512, 1216, 400, 1200, 1216, 0, 0, NUL);

  // ---- image branch ----
  k_gemm128<1, 1, 0, 0><<<dim3(2, 6), 256, 0, stream>>>(imgB, Wi1B, bi1, nullptr, i1B, 2048, 768, 256, 768, 768, 0, 0, NUL);
  k_gemm128<1, 1, 0, 0><<<dim3(2, 8), 256, 0, stream>>>(i1B, Wi2B, bi2, nullptr, i2B, 768, 1024, 256, 1000, 1024, 0, 0, NUL);
  k_gemm128<0, 0, 0, 0><<<dim3(2, 7), 256, 0, stream>>>(i2B, Wi3B, bi3, nullptr, i3F, 1024, 800, 256, 800, 800, 0, 0, NUL);
  k_ln_img<<<dim3(256), 256, 0, stream>>>(i3F, iB, gi, binp);
  k_prep_i<<<dim3(256), 128, 0, stream>>>(iB, gp, bpn, iG, c1B, c2B);

  // ---- pair stage, chunked: P chunk in d_out -> q chunk GEMM (stats fused, XCD-swizzled) ----
  const int CB = 262;                       // m-blocks per chunk
  for (int c = 0; c < 3; ++c) {
    int b0 = c * CB;
    int nb = (782 - b0) < CB ? (782 - b0) : CB;   // 262,262,258
    int r0 = b0 * 128;
    int rows = nb * 128;
    k_pgen<<<dim3((rows * 152 + 255) / 256), 256, 0, stream>>>(PaB, PoB, Pch, r0, rows);
    int mv = (100000 - r0) < rows ? (100000 - r0) : rows;
    k_gemm128<1, 0, 0, 1><<<dim3(7, nb), 256, 0, stream>>>(Pch, Wp2B, bp2, nullptr,
        qB + (size_t)r0 * 800, 1216, 800, mv, 800, 800, 1, 1,
        nullptr, nullptr, nullptr, nullptr, mArr + r0, ivArr + r0);
  }
  k_stats_fin<<<dim3((100096 + 255) / 256), 256, 0, stream>>>(mArr, ivArr);

  // ---- out = LN-fused iG @ q.T (f32, 256 x 100000), XCD-swizzled ----
  k_gemm128<0, 0, 1, 0><<<dim3(2, 782), 256, 0, stream>>>(iG, qB, nullptr, nullptr, (float*)d_out,
      800, 100000, 256, 100000, 100000, 0, 1, mArr, ivArr, c1B, c2B, nullptr, nullptr);
#undef NUL
}

// Round 6
// 1093.786 us; speedup vs baseline: 1.3138x; 1.3138x over previous
//
#include <hip/hip_runtime.h>

#define NN 650
#define NE 100000

typedef short bf16x8_t __attribute__((ext_vector_type(8)));
typedef short s16x4_t __attribute__((ext_vector_type(4)));
typedef float f32x4_t __attribute__((ext_vector_type(4)));

__device__ __forceinline__ unsigned short f2bf(float f) {
  union { float f; unsigned u; } x; x.f = f;
  unsigned r = x.u + 0x7fffu + ((x.u >> 16) & 1u);
  return (unsigned short)(r >> 16);
}
__device__ __forceinline__ float bf2f(unsigned short u) {
  union { unsigned u; float f; } x; x.u = ((unsigned)u) << 16; return x.f;
}

typedef const __attribute__((address_space(1))) unsigned int* gptr_t;
typedef __attribute__((address_space(3))) unsigned int* lptr_t;
__device__ __forceinline__ void gl_lds16(const unsigned short* g, unsigned short* l) {
  __builtin_amdgcn_global_load_lds((gptr_t)g, (lptr_t)l, 16, 0, 0);
}

// ---------------- adjacency build ----------------
__global__ void k_scatter(const int* __restrict__ src, const int* __restrict__ dst,
                          float* __restrict__ C, float* __restrict__ deg) {
  int e = blockIdx.x * 256 + threadIdx.x;
  if (e < NE) {
    int s = src[e], d = dst[e];
    atomicAdd(&C[d * NN + s], 1.0f);
    atomicAdd(&deg[d], 1.0f);
  }
}

// Cn[i][j] = C[i][j]/max(deg[i],1); 768 rows x 672 cols, zero-padded, bf16
__global__ void k_adj_norm(const float* __restrict__ C, const float* __restrict__ deg,
                           unsigned short* __restrict__ Cn) {
  int idx = blockIdx.x * 256 + threadIdx.x;
  if (idx >= 768 * 672) return;
  int i = idx / 672, j = idx - i * 672;
  float v = (i < NN && j < NN) ? C[i * NN + j] / fmaxf(deg[i], 1.0f) : 0.0f;
  Cn[idx] = f2bf(v);
}

// ---------------- fused f32->bf16 converts (12 jobs, 1 launch) ----------------
#define MAXJ 12
struct CvtDesc { const float* src; unsigned short* dst; int Mvalid, Kin, ldi, off, ldo, nElem, nblk; };
struct CvtPack { CvtDesc d[MAXJ]; };
__global__ void k_cvt_all(CvtPack P) {
  int b = blockIdx.x;
  int j = 0;
  while (b >= P.d[j].nblk) { b -= P.d[j].nblk; ++j; }
  const CvtDesc D = P.d[j];
  int idx = b * 256 + threadIdx.x;
  if (idx >= D.nElem) return;
  int r = idx / D.ldo, c = idx - r * D.ldo;
  D.dst[idx] = (r < D.Mvalid && c < D.Kin) ? f2bf(D.src[(size_t)r * D.ldi + D.off + c]) : (unsigned short)0;
}

// ---------------- LDS-tiled transpose: out[c][r] = in[r][c] ----------------
__global__ void k_ttr(const unsigned short* __restrict__ in, unsigned short* __restrict__ out,
                      int ldi, int ldo) {
  __shared__ unsigned short tile[64][65];
  const int c0 = blockIdx.x * 64, r0 = blockIdx.y * 64;
  const int t = threadIdx.x;
  const int rl = t >> 4, cl = (t & 15) * 4;
#pragma unroll
  for (int rr = 0; rr < 4; ++rr) {
    s16x4_t v = *(const s16x4_t*)(in + (size_t)(r0 + rl + rr * 16) * ldi + c0 + cl);
#pragma unroll
    for (int j = 0; j < 4; ++j) tile[rl + rr * 16][cl + j] = (unsigned short)v[j];
  }
  __syncthreads();
  if (r0 + cl < ldo) {
#pragma unroll
    for (int cc = 0; cc < 4; ++cc) {
      int crow = rl + cc * 16;
      unsigned short o[4] = { tile[cl + 0][crow], tile[cl + 1][crow],
                              tile[cl + 2][crow], tile[cl + 3][crow] };
      *(s16x4_t*)(out + (size_t)(c0 + crow) * ldo + r0 + cl) = *(s16x4_t*)o;
    }
  }
}

// ---- P chunk: P[local][k] = relu(Pa[(r0+local)/400][k] + Po[(r0+local)%400][k]) ----
__global__ void k_pgen(const float* __restrict__ Pa, const float* __restrict__ Po,
                       unsigned short* __restrict__ P, int r0, int rows) {
  int g = blockIdx.x * 256 + threadIdx.x;        // group of 8 elements
  if (g >= rows * 152) return;
  int lp = g / 152, k = (g - lp * 152) * 8;
  int p = r0 + lp;
  unsigned short t8[8];
  if (p < 100000) {
    int a = p / 400, o = p - a * 400;
    const float* pa = Pa + (size_t)a * 1216 + k;
    const float* po = Po + (size_t)o * 1216 + k;
    float4 x1 = *(const float4*)(pa);
    float4 x2 = *(const float4*)(pa + 4);
    float4 y1 = *(const float4*)(po);
    float4 y2 = *(const float4*)(po + 4);
    t8[0] = f2bf(fmaxf(x1.x + y1.x, 0.f)); t8[1] = f2bf(fmaxf(x1.y + y1.y, 0.f));
    t8[2] = f2bf(fmaxf(x1.z + y1.z, 0.f)); t8[3] = f2bf(fmaxf(x1.w + y1.w, 0.f));
    t8[4] = f2bf(fmaxf(x2.x + y2.x, 0.f)); t8[5] = f2bf(fmaxf(x2.y + y2.y, 0.f));
    t8[6] = f2bf(fmaxf(x2.z + y2.z, 0.f)); t8[7] = f2bf(fmaxf(x2.w + y2.w, 0.f));
  } else {
#pragma unroll
    for (int j = 0; j < 8; ++j) t8[j] = 0;
  }
  *(bf16x8_t*)(P + (size_t)lp * 1216 + k) = *(bf16x8_t*)t8;
}

// ---- finalize LN stats: S -> mean, SS -> rsqrt(var+eps) ----
__global__ void k_stats_fin(float* __restrict__ S, float* __restrict__ SS) {
  int i = blockIdx.x * 256 + threadIdx.x;
  if (i >= 100096) return;
  float s = S[i], ss = SS[i];
  float m = s * (1.0f / 800.0f);
  float var = ss * (1.0f / 800.0f) - m * m;
  S[i] = m;
  SS[i] = rsqrtf(fmaxf(var, 0.f) + 1e-5f);
}

// ---- split-K finishers ----
// onB = bf16(tmp2 + b2) for rows<650 else 0   (768 x 512)
__global__ void k_fin_on(const float* __restrict__ acc, const float* __restrict__ bias,
                         unsigned short* __restrict__ out) {
  int i = blockIdx.x * 256 + threadIdx.x;
  if (i >= 768 * 512) return;
  int r = i >> 9, c = i & 511;
  out[i] = f2bf(r < 650 ? acc[i] + bias[c] : 0.f);
}
// out = bf16(relu(acc + bias)) with zero pad for c >= Nv
__global__ void k_fin_rb(const float* __restrict__ acc, const float* __restrict__ bias,
                         unsigned short* __restrict__ out, int nElem, int cols, int Nv) {
  int i = blockIdx.x * 256 + threadIdx.x;
  if (i >= nElem) return;
  int c = i % cols;
  float v = 0.f;
  if (c < Nv) v = fmaxf(acc[i] + bias[c], 0.f);
  out[i] = f2bf(v);
}

// ---- iG = bf16(i * gp); c1 = sum(i*gp); c2 = sum(i*bpn). 256 rows, 128 thr/row ----
__global__ void k_prep_i(const unsigned short* __restrict__ iB,
                         const float* __restrict__ gp, const float* __restrict__ bpn,
                         unsigned short* __restrict__ iG,
                         float* __restrict__ c1, float* __restrict__ c2) {
  const int row = blockIdx.x, t = threadIdx.x;   // 128 threads
  float s1 = 0.f, s2 = 0.f;
  if (t < 100) {
    bf16x8_t v = *(const bf16x8_t*)(iB + (size_t)row * 800 + t * 8);
    unsigned short o[8];
#pragma unroll
    for (int j = 0; j < 8; ++j) {
      float f = bf2f((unsigned short)v[j]);
      float g = gp[t * 8 + j];
      s1 += f * g; s2 += f * bpn[t * 8 + j];
      o[j] = f2bf(f * g);
    }
    *(bf16x8_t*)(iG + (size_t)row * 800 + t * 8) = *(bf16x8_t*)o;
  }
#pragma unroll
  for (int off = 32; off > 0; off >>= 1) { s1 += __shfl_down(s1, off); s2 += __shfl_down(s2, off); }
  __shared__ float sh[4];
  int w = t >> 6, lane = t & 63;
  if (lane == 0) { sh[w] = s1; sh[2 + w] = s2; }
  __syncthreads();
  if (t == 0) { c1[row] = sh[0] + sh[1]; c2[row] = sh[2] + sh[3]; }
}

// ---------------- m97-style MFMA GEMM, 2-phase issue-early + LDS XOR swizzle ----------------
// Loop (R4-proven, compiler-known sync only): __syncthreads() [drain+WAR point]
//   -> issue staging of tile t+1 into other buffer -> ds_read + MFMA on tile t.
// LDS swizzle (rule #21: gl_lds writes linearly -> pre-swizzle GLOBAL source slot,
// swizzle READ offset with the same involution): LDS(r,s) holds global(r, s^m(r)),
// m(r) = (r&3)^((r>>2)&3). Write mask m_w and read mask m_r are per-lane constants.
// Fragment reads become exact 2-way bank spread (free) instead of 8-way.
// swz=1: bijective XCD swizzle. QST=1: fused LN-stats epilogue. SK=1: split-K over
// gridDim.z, f32 atomicAdd epilogue (bias/relu applied by finisher kernels).
#define BK 32
template<int OUT_BF, int RELU, int LNF, int QST, int SK>
__launch_bounds__(256)
__global__ void k_gemm128(const unsigned short* __restrict__ A,
                          const unsigned short* __restrict__ B,
                          const float* __restrict__ bias,
                          const float* __restrict__ addb,
                          void* __restrict__ Cout,
                          int K, int ldc,
                          int Mvalid, int Nvalid, int Nstore, int swap, int swz,
                          const float* __restrict__ lnm, const float* __restrict__ lninv,
                          const float* __restrict__ lnc1, const float* __restrict__ lnc2,
                          float* __restrict__ sumP, float* __restrict__ ssP) {
  __shared__ unsigned short As[2][128 * BK];
  __shared__ unsigned short Bs[2][128 * BK];
  const int tid = threadIdx.x;
  const int w = tid >> 6, lane = tid & 63;
  int bx = blockIdx.x, by = blockIdx.y;
  if (swz) {
    int T = gridDim.x * gridDim.y;
    int flat = blockIdx.x + gridDim.x * blockIdx.y;
    int xcd = flat & 7, s = flat >> 3;
    int qq = T >> 3, rr = T & 7;
    int slot = (xcd < rr ? xcd * (qq + 1) : rr * (qq + 1) + (xcd - rr) * qq) + s;
    bx = slot % gridDim.x; by = slot / gridDim.x;
  }
  const int bm = swap ? by : bx;
  const int bn = swap ? bx : by;
  const int m0 = bm * 128, n0 = bn * 128;
  const int wm = w & 1, wn = w >> 1;
  const int lr = lane & 15, q = lane >> 4;

  // staging: row srow, source slot pre-swizzled by m_w = ((lane>>2)&3)^((lane>>4)&3)
  const int srow = w * 32 + (lane >> 2);
  const int mw_ = ((lane >> 2) & 3) ^ ((lane >> 4) & 3);
  const int scol = (((lane & 3) ^ mw_) * 8);
  // fragment read: slot offset qe = (q ^ m_r)*8, m_r = (lane&3)^((lane>>2)&3)
  const int mr_ = (lane & 3) ^ ((lane >> 2) & 3);
  const int qe = ((q ^ mr_) * 8);

  int nt = K / BK, kt0 = 0;
  if (SK) { int Ksl = K / (int)gridDim.z; nt = Ksl / BK; kt0 = blockIdx.z * (Ksl / BK); }

  const unsigned short* Ag = A + (size_t)(m0 + srow) * K + (size_t)kt0 * BK + scol;
  const unsigned short* Bg = B + (size_t)(n0 + srow) * K + (size_t)kt0 * BK + scol;
  const int so0 = (w * 32) * BK;
  const int so1 = (w * 32 + 16) * BK;

  f32x4_t acc[4][4];
#pragma unroll
  for (int r = 0; r < 4; ++r)
#pragma unroll
    for (int t = 0; t < 4; ++t) { f32x4_t z = {0.f, 0.f, 0.f, 0.f}; acc[r][t] = z; }

  // prologue: stage tile 0 into buffer 0
  gl_lds16(Ag, &As[0][so0]); gl_lds16(Ag + 16 * (size_t)K, &As[0][so1]);
  gl_lds16(Bg, &Bs[0][so0]); gl_lds16(Bg + 16 * (size_t)K, &Bs[0][so1]);
  Ag += BK; Bg += BK;

  for (int t = 0; t < nt; ++t) {
    const int cur = t & 1;
    __syncthreads();   // drains tile-t staging loads; joins waves (WAR-safe for restage)
    if (t + 1 < nt) {  // issue next tile's staging NOW; lands while we compute tile t
      const int nxt = cur ^ 1;
      gl_lds16(Ag, &As[nxt][so0]); gl_lds16(Ag + 16 * (size_t)K, &As[nxt][so1]);
      gl_lds16(Bg, &Bs[nxt][so0]); gl_lds16(Bg + 16 * (size_t)K, &Bs[nxt][so1]);
      Ag += BK; Bg += BK;
    }
    bf16x8_t af[4], bfv[4];
#pragma unroll
    for (int r = 0; r < 4; ++r)
      af[r] = *(const bf16x8_t*)(&As[cur][(wm * 64 + r * 16 + lr) * BK + qe]);
#pragma unroll
    for (int tt = 0; tt < 4; ++tt)
      bfv[tt] = *(const bf16x8_t*)(&Bs[cur][(wn * 64 + tt * 16 + lr) * BK + qe]);
#pragma unroll
    for (int r = 0; r < 4; ++r)
#pragma unroll
      for (int tt = 0; tt < 4; ++tt)
        acc[r][tt] = __builtin_amdgcn_mfma_f32_16x16x32_bf16(af[r], bfv[tt], acc[r][tt], 0, 0, 0);
  }

  if (SK) {
    // split-K partial: accumulate into f32 Cout (pre-zeroed); bias/relu in finisher
#pragma unroll
    for (int r = 0; r < 4; ++r)
#pragma unroll
      for (int t = 0; t < 4; ++t)
#pragma unroll
        for (int e = 0; e < 4; ++e) {
          int gm = m0 + wm * 64 + r * 16 + q * 4 + e;
          int gn = n0 + wn * 64 + t * 16 + lr;
          if (gm < Mvalid && gn < Nvalid)
            atomicAdd((float*)Cout + (size_t)gm * ldc + gn, acc[r][t][e]);
        }
  } else if (QST) {
    // epilogue with fused row-stats (store + per-row sum / sumsq of acc+bias)
#pragma unroll
    for (int r = 0; r < 4; ++r) {
#pragma unroll
      for (int e = 0; e < 4; ++e) {
        const int gm = m0 + wm * 64 + r * 16 + q * 4 + e;
        float s = 0.f, ss = 0.f;
#pragma unroll
        for (int t = 0; t < 4; ++t) {
          const int gn = n0 + wn * 64 + t * 16 + lr;
          float v = 0.f;
          if (gm < Mvalid && gn < Nvalid) v = acc[r][t][e] + bias[gn];
          if (gn < Nstore)
            ((unsigned short*)Cout)[(size_t)gm * ldc + gn] = f2bf(v);
          s += v; ss += v * v;
        }
#pragma unroll
        for (int m = 1; m < 16; m <<= 1) {
          s += __shfl_xor(s, m);
          ss += __shfl_xor(ss, m);
        }
        if (lr == 0 && gm < Mvalid) {
          atomicAdd(&sumP[gm], s);
          atomicAdd(&ssP[gm], ss);
        }
      }
    }
  } else {
#pragma unroll
    for (int r = 0; r < 4; ++r) {
#pragma unroll
      for (int t = 0; t < 4; ++t) {
#pragma unroll
        for (int e = 0; e < 4; ++e) {
          int gm = m0 + wm * 64 + r * 16 + q * 4 + e;
          int gn = n0 + wn * 64 + t * 16 + lr;
          if (gn < Nstore) {
            float v = 0.f;
            if (gm < Mvalid && gn < Nvalid) {
              v = acc[r][t][e];
              if (LNF) {
                v = lninv[gn] * (v - lnm[gn] * lnc1[gm]) + lnc2[gm];
              } else {
                if (bias) v += bias[gn];
                if (addb) v += addb[(size_t)gm * ldc + gn];
                if (RELU) v = fmaxf(v, 0.f);
              }
            }
            if (OUT_BF) ((unsigned short*)Cout)[(size_t)gm * ldc + gn] = f2bf(v);
            else        ((float*)Cout)[(size_t)gm * ldc + gn] = v;
          }
        }
      }
    }
  }
}

// ---------------- LayerNorm over D=800 (f32 in + bias, bf16 out) — image branch ----------------
__global__ void k_ln_img(const float* __restrict__ in, const float* __restrict__ bb,
                         unsigned short* __restrict__ out,
                         const float* __restrict__ g, const float* __restrict__ b) {
  const int row = blockIdx.x, t = threadIdx.x;
  float v[4]; float s = 0.f, ss = 0.f; int j = 0;
  for (int idx = t; idx < 800; idx += 256, ++j) {
    float x = in[(size_t)row * 800 + idx] + bb[idx];
    v[j] = x; s += x; ss += x * x;
  }
#pragma unroll
  for (int off = 32; off > 0; off >>= 1) {
    s += __shfl_down(s, off);
    ss += __shfl_down(ss, off);
  }
  __shared__ float sh[8];
  int wave = t >> 6, lane = t & 63;
  if (lane == 0) { sh[wave] = s; sh[4 + wave] = ss; }
  __syncthreads();
  if (t == 0) {
    float S = sh[0] + sh[1] + sh[2] + sh[3];
    float SS = sh[4] + sh[5] + sh[6] + sh[7];
    float m = S * (1.0f / 800.0f);
    float var = SS * (1.0f / 800.0f) - m * m;
    sh[0] = m; sh[1] = rsqrtf(fmaxf(var, 0.f) + 1e-5f);
  }
  __syncthreads();
  float m = sh[0], inv = sh[1];
  j = 0;
  for (int idx = t; idx < 800; idx += 256, ++j) {
    float y = (v[j] - m) * inv * g[idx] + b[idx];
    out[(size_t)row * 800 + idx] = f2bf(y);
  }
}

// ---------------- host ----------------
extern "C" void kernel_launch(void* const* d_in, const int* in_sizes, int n_in,
                              void* d_out, int out_size, void* d_ws, size_t ws_size,
                              hipStream_t stream) {
  (void)in_sizes; (void)n_in; (void)out_size; (void)ws_size;
  const float* img  = (const float*)d_in[0];
  const float* nodes= (const float*)d_in[1];
  const int* esrc   = (const int*)d_in[2];
  const int* edst   = (const int*)d_in[3];
  const float* W1l  = (const float*)d_in[4];
  const float* b1   = (const float*)d_in[5];
  const float* W1r  = (const float*)d_in[6];
  const float* W2l  = (const float*)d_in[7];
  const float* b2   = (const float*)d_in[8];
  const float* W2r  = (const float*)d_in[9];
  const float* Wp1  = (const float*)d_in[10];
  const float* bp1  = (const float*)d_in[11];
  const float* Wp2  = (const float*)d_in[12];
  const float* bp2  = (const float*)d_in[13];
  const float* gp   = (const float*)d_in[14];
  const float* bpn  = (const float*)d_in[15];
  const float* Wi1  = (const float*)d_in[16];
  const float* bi1  = (const float*)d_in[17];
  const float* Wi2  = (const float*)d_in[18];
  const float* bi2  = (const float*)d_in[19];
  const float* Wi3  = (const float*)d_in[20];
  const float* bi3  = (const float*)d_in[21];
  const float* gi   = (const float*)d_in[22];
  const float* binp = (const float*)d_in[23];

  char* wsp = (char*)d_ws;
  auto alloc = [&](size_t bytes) -> void* {
    void* p = (void*)wsp; wsp += (bytes + 255) & ~(size_t)255; return p;
  };
  // persistent (live across the pair stage)
  unsigned short* onB    = (unsigned short*)alloc((size_t)768 * 512 * 2);
  unsigned short* Wp1LB  = (unsigned short*)alloc((size_t)1280 * 512 * 2);
  unsigned short* Wp1RB  = (unsigned short*)alloc((size_t)1280 * 512 * 2);
  unsigned short* Wp2B   = (unsigned short*)alloc((size_t)896 * 1216 * 2);
  float* PaB             = (float*)alloc((size_t)256 * 1216 * 4);
  float* PoB             = (float*)alloc((size_t)512 * 1216 * 4);
  unsigned short* imgB   = (unsigned short*)alloc((size_t)256 * 2048 * 2);
  unsigned short* Wi1B   = (unsigned short*)alloc((size_t)768 * 2048 * 2);
  unsigned short* Wi2B   = (unsigned short*)alloc((size_t)1024 * 768 * 2);
  unsigned short* Wi3B   = (unsigned short*)alloc((size_t)896 * 1024 * 2);
  unsigned short* i1B    = (unsigned short*)alloc((size_t)256 * 768 * 2);
  unsigned short* i2B    = (unsigned short*)alloc((size_t)256 * 1024 * 2);
  float* i3F             = (float*)alloc((size_t)256 * 800 * 4);
  unsigned short* iB     = (unsigned short*)alloc((size_t)256 * 800 * 2);
  unsigned short* iG     = (unsigned short*)alloc((size_t)256 * 800 * 2);
  float* c1B             = (float*)alloc(256 * 4);
  float* c2B             = (float*)alloc(256 * 4);
  float* mArr            = (float*)alloc((size_t)100096 * 4);
  float* ivArr           = (float*)alloc((size_t)100096 * 4);
  unsigned short* qB     = (unsigned short*)alloc((size_t)100096 * 800 * 2);

  // node-stage scratch overlays the qB region (dead before first qB write)
  char* swp = (char*)qB;
  auto salloc = [&](size_t bytes) -> void* {
    void* p = (void*)swp; swp += (bytes + 255) & ~(size_t)255; return p;
  };
  float* adjC            = (float*)salloc((size_t)NN * NN * 4);
  float* deg             = (float*)salloc(NN * 4);
  unsigned short* Cn     = (unsigned short*)salloc((size_t)768 * 672 * 2);
  unsigned short* nodesB = (unsigned short*)salloc((size_t)768 * 512 * 2);
  unsigned short* nodesT = (unsigned short*)salloc((size_t)512 * 672 * 2);
  unsigned short* agg1   = (unsigned short*)salloc((size_t)768 * 512 * 2);
  float* tmp1            = (float*)salloc((size_t)768 * 4096 * 4);
  unsigned short* hB     = (unsigned short*)salloc((size_t)768 * 4096 * 2);
  unsigned short* hT     = (unsigned short*)salloc((size_t)4096 * 672 * 2);
  unsigned short* agg2   = (unsigned short*)salloc((size_t)768 * 4096 * 2);
  float* tmp2            = (float*)salloc((size_t)768 * 512 * 4);
  unsigned short* W1lB   = (unsigned short*)salloc((size_t)4096 * 512 * 2);
  unsigned short* W1rB   = (unsigned short*)salloc((size_t)4096 * 512 * 2);
  unsigned short* W2lB   = (unsigned short*)salloc((size_t)512 * 4096 * 2);
  unsigned short* W2rB   = (unsigned short*)salloc((size_t)512 * 4096 * 2);
  float* F1              = (float*)salloc((size_t)256 * 768 * 4);   // image split-K scratch
  float* F2              = (float*)salloc((size_t)256 * 1024 * 4);

  // P chunk scratch lives in d_out (102.4 MB; scratch-legal until the final GEMM)
  unsigned short* Pch = (unsigned short*)d_out;  // max 262*128 rows * 1216 * 2 = 81.6 MB

  hipMemsetAsync(adjC, 0, (size_t)NN * NN * 4, stream);
  hipMemsetAsync(deg, 0, NN * 4, stream);
  hipMemsetAsync(mArr, 0, (size_t)100096 * 4, stream);   // row-sum accumulators
  hipMemsetAsync(ivArr, 0, (size_t)100096 * 4, stream);  // row-sumsq accumulators
  hipMemsetAsync(tmp2, 0, (size_t)768 * 512 * 4, stream); // split-K accumulators
  hipMemsetAsync(F1, 0, (size_t)256 * 768 * 4, stream);
  hipMemsetAsync(F2, 0, (size_t)256 * 1024 * 4, stream);
  hipMemsetAsync(i3F, 0, (size_t)256 * 800 * 4, stream);

  k_scatter<<<dim3((NE + 255) / 256), 256, 0, stream>>>(esrc, edst, adjC, deg);
  k_adj_norm<<<dim3((768 * 672 + 255) / 256), 256, 0, stream>>>(adjC, deg, Cn);

  // ---- fused converts (one launch) ----
  {
    CvtPack pk; int nj = 0, tot = 0;
    auto addj = [&](const float* s, unsigned short* d, int Mv, int Mp, int Kin, int ldi, int off, int ldo) {
      int ne = Mp * ldo, nb = (ne + 255) / 256;
      pk.d[nj++] = { s, d, Mv, Kin, ldi, off, ldo, ne, nb };
      tot += nb;
    };
    addj(nodes, nodesB, 650, 768, 512, 512, 0, 512);
    addj(W1l, W1lB, 4096, 4096, 512, 512, 0, 512);
    addj(W1r, W1rB, 4096, 4096, 512, 512, 0, 512);
    addj(W2l, W2lB, 512, 512, 4096, 4096, 0, 4096);
    addj(W2r, W2rB, 512, 512, 4096, 4096, 0, 4096);
    addj(Wp1, Wp1LB, 1200, 1280, 512, 1024, 0, 512);
    addj(Wp1, Wp1RB, 1200, 1280, 512, 1024, 512, 512);
    addj(Wp2, Wp2B, 800, 896, 1200, 1200, 0, 1216);
    addj(Wi1, Wi1B, 768, 768, 2048, 2048, 0, 2048);
    addj(Wi2, Wi2B, 1000, 1024, 768, 768, 0, 768);
    addj(Wi3, Wi3B, 800, 896, 1000, 1000, 0, 1024);
    addj(img, imgB, 256, 256, 2048, 2048, 0, 2048);
    k_cvt_all<<<dim3(tot), 256, 0, stream>>>(pk);
  }

  // nodesT[feat][node] from nodesB; out 512 x 672
  k_ttr<<<dim3(512 / 64, (672 + 63) / 64), 256, 0, stream>>>(nodesB, nodesT, 512, 672);

#define NUL nullptr, nullptr, nullptr, nullptr, nullptr, nullptr
  // ---- node stage (scratch region) ----
  k_gemm128<1, 0, 0, 0, 0><<<dim3(6, 4), 256, 0, stream>>>(Cn, nodesT, nullptr, nullptr, agg1, 672, 512, 650, 512, 512, 0, 0, NUL);
  k_gemm128<0, 0, 0, 0, 0><<<dim3(6, 32), 256, 0, stream>>>(agg1, W1lB, b1, nullptr, tmp1, 512, 4096, 650, 4096, 4096, 0, 0, NUL);
  k_gemm128<1, 1, 0, 0, 0><<<dim3(6, 32), 256, 0, stream>>>(nodesB, W1rB, nullptr, tmp1, hB, 512, 4096, 650, 4096, 4096, 0, 0, NUL);
  k_ttr<<<dim3(4096 / 64, (672 + 63) / 64), 256, 0, stream>>>(hB, hT, 4096, 672);
  k_gemm128<1, 0, 0, 0, 0><<<dim3(6, 32), 256, 0, stream>>>(Cn, hT, nullptr, nullptr, agg2, 672, 4096, 650, 4096, 4096, 0, 0, NUL);
  // split-K (x8): tmp2 += agg2@W2l ; tmp2 += hB@W2r ; then onB = bf16(tmp2 + b2)
  k_gemm128<0, 0, 0, 0, 1><<<dim3(6, 4, 8), 256, 0, stream>>>(agg2, W2lB, nullptr, nullptr, tmp2, 4096, 512, 650, 512, 512, 0, 0, NUL);
  k_gemm128<0, 0, 0, 0, 1><<<dim3(6, 4, 8), 256, 0, stream>>>(hB, W2rB, nullptr, nullptr, tmp2, 4096, 512, 650, 512, 512, 0, 0, NUL);
  k_fin_on<<<dim3((768 * 512 + 255) / 256), 256, 0, stream>>>(tmp2, b2, onB);
  // Pa = attr @ Wp1L.T + bp1 ; Po = obj @ Wp1R.T (f32, ld 1216, cols 1200..1215 zero)
  k_gemm128<0, 0, 0, 0, 0><<<dim3(2, 10), 256, 0, stream>>>(onB, Wp1LB, bp1, nullptr, PaB, 512, 1216, 250, 1200, 1216, 0, 0, NUL);
  k_gemm128<0, 0, 0, 0, 0><<<dim3(4, 10), 256, 0, stream>>>(onB + 250 * 512, Wp1RB, nullptr, nullptr, PoB, 512, 1216, 400, 1200, 1216, 0, 0, NUL);

  // ---- image branch (split-K x8 + relu/bias finishers) ----
  k_gemm128<0, 0, 0, 0, 1><<<dim3(2, 6, 8), 256, 0, stream>>>(imgB, Wi1B, nullptr, nullptr, F1, 2048, 768, 256, 768, 768, 0, 0, NUL);
  k_fin_rb<<<dim3((256 * 768 + 255) / 256), 256, 0, stream>>>(F1, bi1, i1B, 256 * 768, 768, 768);
  k_gemm128<0, 0, 0, 0, 1><<<dim3(2, 8, 8), 256, 0, stream>>>(i1B, Wi2B, nullptr, nullptr, F2, 768, 1024, 256, 1000, 1024, 0, 0, NUL);
  k_fin_rb<<<dim3((256 * 1024 + 255) / 256), 256, 0, stream>>>(F2, bi2, i2B, 256 * 1024, 1024, 1000);
  k_gemm128<0, 0, 0, 0, 1><<<dim3(2, 7, 8), 256, 0, stream>>>(i2B, Wi3B, nullptr, nullptr, i3F, 1024, 800, 256, 800, 800, 0, 0, NUL);
  k_ln_img<<<dim3(256), 256, 0, stream>>>(i3F, bi3, iB, gi, binp);
  k_prep_i<<<dim3(256), 128, 0, stream>>>(iB, gp, bpn, iG, c1B, c2B);

  // ---- pair stage, chunked: P chunk in d_out -> q chunk GEMM (stats fused, XCD-swizzled) ----
  const int CB = 262;                       // m-blocks per chunk
  for (int c = 0; c < 3; ++c) {
    int b0 = c * CB;
    int nb = (782 - b0) < CB ? (782 - b0) : CB;   // 262,262,258
    int r0 = b0 * 128;
    int rows = nb * 128;
    k_pgen<<<dim3((rows * 152 + 255) / 256), 256, 0, stream>>>(PaB, PoB, Pch, r0, rows);
    int mv = (100000 - r0) < rows ? (100000 - r0) : rows;
    k_gemm128<1, 0, 0, 1, 0><<<dim3(7, nb), 256, 0, stream>>>(Pch, Wp2B, bp2, nullptr,
        qB + (size_t)r0 * 800, 1216, 800, mv, 800, 800, 1, 1,
        nullptr, nullptr, nullptr, nullptr, mArr + r0, ivArr + r0);
  }
  k_stats_fin<<<dim3((100096 + 255) / 256), 256, 0, stream>>>(mArr, ivArr);

  // ---- out = LN-fused iG @ q.T (f32, 256 x 100000), XCD-swizzled ----
  k_gemm128<0, 0, 1, 0, 0><<<dim3(2, 782), 256, 0, stream>>>(iG, qB, nullptr, nullptr, (float*)d_out,
      800, 100000, 256, 100000, 100000, 0, 1, mArr, ivArr, c1B, c2B, nullptr, nullptr);
#undef NUL
}